// Round 1
// 131750.195 us; speedup vs baseline: 1.4411x; 1.4411x over previous
//
#include <hip/hip_runtime.h>
#include <cstddef>

// ---------------- problem constants ----------------
// B=32, T_IN=512, T_OUT=800, N_MEL=80, ENC=512, ARNN=DRNN=1024, PRE=256,
// ATT=128, LOCF=32, LOCK=31.  4*ARNN = 4096 gate rows.

// ---------------- workspace layout (float offsets) ----------------
// WT_ATT: [128 blocks][1792 k][32 cols]  (col = gate*8 + jj)
// WT_DEC: [128 blocks][2560 k][32 cols]
constexpr size_t WT_ATT = 0;                         // 7340032
constexpr size_t WT_DEC = 7340032;                   // +10485760
constexpr size_t PREN_O = 17825792;                  // [800][32][256]
constexpr size_t PMEMT  = 24379392;                  // [32][128][512]
constexpr size_t W1T    = 26476544;                  // [80][256]
constexpr size_t W2T    = 26497024;                  // [256][256]
constexpr size_t QWT    = 26562560;                  // [1024][128]
constexpr size_t PWT    = 26693632;                  // [1536][96]
constexpr size_t MEMWT  = 26841088;                  // [512][128]
constexpr size_t XATT   = 26906624;                  // [2][32][1792] (pren|actx|ah)
constexpr size_t XDEC   = 27021312;                  // [2][32][2560] (ah|dh|actx)
constexpr size_t AH_O   = 27185152;                  // [32][1024]
constexpr size_t AC_O   = 27217920;                  // [32][1024] block-private
constexpr size_t DH_O   = 27250688;                  // [32][1024]
constexpr size_t DC_O   = 27283456;                  // [32][1024] block-private
constexpr size_t AWC_O  = 27316224;                  // [2][32][512]
constexpr size_t ACTX_O = 27348992;                  // [2][32][512]
constexpr size_t ENER_O = 27381760;                  // [32][512]
constexpr size_t LOC_O  = 27398144;                  // [32][512][32]
constexpr size_t BAR_O  = 27922432;                  // 4224 u32

constexpr size_t MEL_OUT = 0;                 // [32][80][800]
constexpr size_t GATE_OUT = 2048000;          // [32][800]
constexpr size_t ALIGN_OUT = 2073600;         // [32][800][512]

// ---------------- coherent (MALL-bypass) accessors ----------------
__device__ __forceinline__ float gload(const float* p_) {
  return __hip_atomic_load(p_, __ATOMIC_RELAXED, __HIP_MEMORY_SCOPE_AGENT);
}
__device__ __forceinline__ void gstore(float* p_, float v) {
  __hip_atomic_store(p_, v, __ATOMIC_RELAXED, __HIP_MEMORY_SCOPE_AGENT);
}

// ---------------- contention-free grid barrier (no fences) ----------------
// 512 blocks: 16 count lines (stride 8 u32 = 32B), 512 release lines
// (stride 8 u32).  Total = 128 + 4096 = 4224 u32 (fits BAR region exactly).
__device__ __forceinline__ void gsync(float* ws, unsigned& epoch) {
  unsigned* cnt = (unsigned*)(ws + BAR_O);         // cnt[g*8], g<16
  unsigned* rel = (unsigned*)(ws + BAR_O) + 128;   // rel[i*8], i<512
  __syncthreads();
  const int tid = threadIdx.x, bid = blockIdx.x;
  ++epoch;
  if (tid == 0)
    __hip_atomic_fetch_add(&cnt[(bid & 15) * 8], 1u, __ATOMIC_RELAXED,
                           __HIP_MEMORY_SCOPE_AGENT);
  if (bid == 0) {
    if (tid < 64) {
      const unsigned tgt = epoch * 32u;  // 512 blocks / 16 lines
      bool done;
      do {
        unsigned v = (tid < 16) ? __hip_atomic_load(&cnt[tid * 8], __ATOMIC_RELAXED,
                                                    __HIP_MEMORY_SCOPE_AGENT)
                                : tgt;
        done = v >= tgt;
        if (!done) __builtin_amdgcn_s_sleep(2);
      } while (__ballot(done) != ~0ull);
      for (int rr = tid; rr < 512; rr += 64)
        __hip_atomic_store(&rel[rr * 8], epoch, __ATOMIC_RELAXED,
                           __HIP_MEMORY_SCOPE_AGENT);
    }
  } else if (tid == 0) {
    while (__hip_atomic_load(&rel[bid * 8], __ATOMIC_RELAXED,
                             __HIP_MEMORY_SCOPE_AGENT) < epoch)
      __builtin_amdgcn_s_sleep(4);
  }
  __syncthreads();
}

// ---------------- helpers ----------------
__device__ __forceinline__ float sigf(float x) {
  float cx = fminf(fmaxf(x, -30.f), 30.f);
  return 1.f / (1.f + __expf(-cx));
}
__device__ __forceinline__ float tanh_f(float x) {
  float cx = fminf(fmaxf(x, -15.f), 15.f);
  float e = __expf(2.f * cx);
  return (e - 1.f) / (e + 1.f);
}

// ---------------- fused GEMM + LSTM cell (batch-half version) ------------
// Block (g, hh) owns 32 gate-cols (col = gate*8 + jj, j = g*8+jj) and the
// 16-batch half hh.  Z = X_half·W for 16 b × 32 cols, K-reduced 32 ways.
// X: [16][K] bypass (pre-offset by caller).  WB: [K][32] contiguous, cached
// (the hh=0/hh=1 pair reads identical W -> same-XCD L2/L1 absorbs).
__device__ __forceinline__ void fused_block(
    const float* __restrict__ X, const int K, const float* __restrict__ WB,
    const int g, const int hh, const float* __restrict__ bih,
    const float* __restrict__ bhh, float* __restrict__ cst,
    float* __restrict__ d0, const int s0, float* __restrict__ d1, const int s1,
    float* __restrict__ d2, const int s2, const int tid,
    float* __restrict__ sm) {
  float* Xs = sm;           // [128][20] (Xs[k][b]) = 2560
  float* Ws = sm + 2560;    // [128][36] (Ws[k][c]) = 4608
  const int cg = tid & 3, bg = (tid >> 2) & 1, ks = tid >> 3;  // 32-way K split
  float acc[8][8];
#pragma unroll
  for (int ci = 0; ci < 8; ++ci)
#pragma unroll
    for (int bi = 0; bi < 8; ++bi) acc[ci][bi] = 0.f;

  const int nc = K >> 7;
  const int kloc = tid & 127, brow = tid >> 7;
  const float* xb = X + (size_t)brow * K + kloc;
  float px[8];
  float4 pw[4];
#pragma unroll
  for (int i = 0; i < 8; ++i) px[i] = gload(xb + (size_t)(2 * i) * K);
#pragma unroll
  for (int j = 0; j < 4; ++j)
    pw[j] = *(const float4*)(WB + (size_t)tid * 4 + j * 1024);

#pragma unroll 1
  for (int c = 0; c < nc; ++c) {
    __syncthreads();
#pragma unroll
    for (int i = 0; i < 8; ++i) Xs[kloc * 20 + brow + 2 * i] = px[i];
#pragma unroll
    for (int j = 0; j < 4; ++j) {
      const int ff = tid + 256 * j;           // float4 index in chunk
      *(float4*)(Ws + (ff >> 3) * 36 + (ff & 7) * 4) = pw[j];
    }
    __syncthreads();
    if (c + 1 < nc) {
      const float* xb2 = xb + (c + 1) * 128;
#pragma unroll
      for (int i = 0; i < 8; ++i) px[i] = gload(xb2 + (size_t)(2 * i) * K);
      const float* wb2 = WB + (size_t)(c + 1) * 4096 + (size_t)tid * 4;
#pragma unroll
      for (int j = 0; j < 4; ++j) pw[j] = *(const float4*)(wb2 + j * 1024);
    }
#pragma unroll
    for (int i = 0; i < 4; ++i) {
      const int k = i * 32 + ks;
      const float4 wA = *(const float4*)(Ws + k * 36 + cg * 8);
      const float4 wBv = *(const float4*)(Ws + k * 36 + cg * 8 + 4);
      const float4 xA = *(const float4*)(Xs + k * 20 + bg * 8);
      const float4 xBv = *(const float4*)(Xs + k * 20 + bg * 8 + 4);
      const float wr[8] = {wA.x, wA.y, wA.z, wA.w, wBv.x, wBv.y, wBv.z, wBv.w};
      const float xr[8] = {xA.x, xA.y, xA.z, xA.w, xBv.x, xBv.y, xBv.z, xBv.w};
#pragma unroll
      for (int ci = 0; ci < 8; ++ci)
#pragma unroll
        for (int bi = 0; bi < 8; ++bi)
          acc[ci][bi] = fmaf(wr[ci], xr[bi], acc[ci][bi]);
    }
  }
  // intra-wave reduce over the 8 ks values resident in each wave
#pragma unroll
  for (int ci = 0; ci < 8; ++ci)
#pragma unroll
    for (int bi = 0; bi < 8; ++bi) {
      float v = acc[ci][bi];
      v += __shfl_xor(v, 8);
      v += __shfl_xor(v, 16);
      v += __shfl_xor(v, 32);
      acc[ci][bi] = v;
    }
  __syncthreads();  // done reading Xs/Ws; overlay with reduction scratch
  float* red = sm;        // [512 outputs][5] (stride 5 kills bank aliasing)
  float* zs = sm + 2560;  // [512] = z[b][col]
  const int lane = tid & 63, wv = tid >> 6;
  if (lane < 8) {  // lanes holding the wave-summed tiles
#pragma unroll
    for (int ci = 0; ci < 8; ++ci)
#pragma unroll
      for (int bi = 0; bi < 8; ++bi)
        red[((bg * 8 + bi) * 32 + cg * 8 + ci) * 5 + wv] = acc[ci][bi];
  }
  __syncthreads();
#pragma unroll
  for (int m = 0; m < 2; ++m) {
    const int o = tid + 256 * m;
    zs[o] = red[o * 5] + red[o * 5 + 1] + red[o * 5 + 2] + red[o * 5 + 3];
  }
  __syncthreads();
  // cell: 128 threads = 8 jj × 16 b
  if (tid < 128) {
    const int bb = tid & 15, jj = tid >> 4;
    const int j = g * 8 + jj;
    const int b = hh * 16 + bb;
    const float zi = zs[bb * 32 + jj] + bih[j] + bhh[j];
    const float zf = zs[bb * 32 + 8 + jj] + bih[1024 + j] + bhh[1024 + j];
    const float zg = zs[bb * 32 + 16 + jj] + bih[2048 + j] + bhh[2048 + j];
    const float zo = zs[bb * 32 + 24 + jj] + bih[3072 + j] + bhh[3072 + j];
    const float cp = cst[(size_t)b * 1024 + j];  // block-private: plain cached
    const float ct = sigf(zf) * cp + sigf(zi) * tanh_f(zg);
    const float ho = sigf(zo) * tanh_f(ct);
    cst[(size_t)b * 1024 + j] = ct;
    gstore(d0 + (size_t)b * s0 + j, ho);
    if (d1) gstore(d1 + (size_t)b * s1 + j, ho);
    if (d2) gstore(d2 + (size_t)b * s2 + j, ho);
  }
}

// ---------------- setup kernels ----------------
__global__ __launch_bounds__(256) void k_small(
    const float* __restrict__ w1, const float* __restrict__ w2,
    const float* __restrict__ qw, const float* __restrict__ memw,
    const float* __restrict__ projw, const float* __restrict__ gatew,
    float* __restrict__ ws) {
  size_t i = (size_t)blockIdx.x * 256 + threadIdx.x;
  if (i < 20480) { size_t j = i & 255, m = i >> 8; ws[W1T + m * 256 + j] = w1[j * 80 + m]; return; }
  i -= 20480;
  if (i < 65536) { size_t j = i & 255, k = i >> 8; ws[W2T + k * 256 + j] = w2[j * 256 + k]; return; }
  i -= 65536;
  if (i < 131072) { size_t j = i & 127, k = i >> 7; ws[QWT + k * 128 + j] = qw[j * 1024 + k]; return; }
  i -= 131072;
  if (i < 65536) { size_t a = i & 127, e = i >> 7; ws[MEMWT + e * 128 + a] = memw[a * 512 + e]; return; }
  i -= 65536;
  if (i < 147456) {
    size_t o = i % 96, k = i / 96;
    float v = 0.f;
    if (o < 80) v = projw[o * 1536 + k];
    else if (o == 80) v = gatew[k];
    ws[PWT + k * 96 + o] = v;
  }
}

// weight transposes: input-indexed (coalesced reads, scattered writes)
__device__ __forceinline__ size_t att_out(int gcol, int kout) {
  const int gate = gcol >> 10, g = (gcol & 1023) >> 3, jj = gcol & 7;
  return WT_ATT + ((size_t)g * 1792 + kout) * 32 + gate * 8 + jj;
}
__device__ __forceinline__ size_t dec_out(int gcol, int kout) {
  const int gate = gcol >> 10, g = (gcol & 1023) >> 3, jj = gcol & 7;
  return WT_DEC + ((size_t)g * 2560 + kout) * 32 + gate * 8 + jj;
}
__global__ __launch_bounds__(256) void k_tr_a_wih(const float* __restrict__ w,
                                                  float* __restrict__ ws) {
  const int i = blockIdx.x * 256 + threadIdx.x;  // < 4096*768
  const int gcol = i / 768, k = i - gcol * 768;
  ws[att_out(gcol, k)] = w[i];
}
__global__ __launch_bounds__(256) void k_tr_a_whh(const float* __restrict__ w,
                                                  float* __restrict__ ws) {
  const int i = blockIdx.x * 256 + threadIdx.x;  // < 4096*1024
  const int gcol = i >> 10, kin = i & 1023;
  ws[att_out(gcol, 768 + kin)] = w[i];
}
__global__ __launch_bounds__(256) void k_tr_d_wih(const float* __restrict__ w,
                                                  float* __restrict__ ws) {
  const int i = blockIdx.x * 256 + threadIdx.x;  // < 4096*1536
  const int gcol = i / 1536, kin = i - gcol * 1536;
  const int kout = (kin < 1024) ? kin : kin + 1024;  // actx part -> 2048..2559
  ws[dec_out(gcol, kout)] = w[i];
}
__global__ __launch_bounds__(256) void k_tr_d_whh(const float* __restrict__ w,
                                                  float* __restrict__ ws) {
  const int i = blockIdx.x * 256 + threadIdx.x;  // < 4096*1024
  const int gcol = i >> 10, kin = i & 1023;
  ws[dec_out(gcol, 1024 + kin)] = w[i];
}

__global__ __launch_bounds__(256) void k_prenet(const float* __restrict__ din,
                                                float* __restrict__ ws) {
  __shared__ float h1[8][257];
  const int tg = blockIdx.x, b = blockIdx.y, j = threadIdx.x;
  float acc[8] = {0, 0, 0, 0, 0, 0, 0, 0};
  for (int m = 0; m < 80; ++m) {
    const float w = ws[W1T + m * 256 + j];
#pragma unroll
    for (int q = 0; q < 8; ++q) {
      const int t = tg * 8 + q;
      const float x = (t > 0) ? din[((size_t)b * 80 + m) * 800 + (t - 1)] : 0.f;
      acc[q] = fmaf(x, w, acc[q]);
    }
  }
#pragma unroll
  for (int q = 0; q < 8; ++q) h1[q][j] = fmaxf(acc[q], 0.f);
  __syncthreads();
  float a2[8] = {0, 0, 0, 0, 0, 0, 0, 0};
  for (int k = 0; k < 256; ++k) {
    const float w = ws[W2T + k * 256 + j];
#pragma unroll
    for (int q = 0; q < 8; ++q) a2[q] = fmaf(h1[q][k], w, a2[q]);
  }
#pragma unroll
  for (int q = 0; q < 8; ++q) {
    const int t = tg * 8 + q;
    ws[PREN_O + ((size_t)t * 32 + b) * 256 + j] = fmaxf(a2[q], 0.f);
  }
}

__global__ __launch_bounds__(256) void k_pmem(const float* __restrict__ mem,
                                              float* __restrict__ ws) {
  __shared__ float mt[16 * 516];
  const int b = blockIdx.x, tc = blockIdx.y, tid = threadIdx.x;
  const int ti0 = tc * 16;
  for (int i = tid; i < 16 * 128; i += 256) {
    const int r = i >> 7, c = i & 127;
    *(float4*)(mt + r * 516 + c * 4) =
        *(const float4*)(mem + ((size_t)b * 512 + ti0 + r) * 512 + c * 4);
  }
  __syncthreads();
  const int a = tid & 127, th = tid >> 7;
  float acc[8] = {0, 0, 0, 0, 0, 0, 0, 0};
  for (int e = 0; e < 512; ++e) {
    const float w = ws[MEMWT + (size_t)e * 128 + a];
#pragma unroll
    for (int q = 0; q < 8; ++q) acc[q] = fmaf(w, mt[(th * 8 + q) * 516 + e], acc[q]);
  }
#pragma unroll
  for (int q = 0; q < 8; ++q)
    ws[PMEMT + ((size_t)b * 128 + a) * 512 + ti0 + th * 8 + q] = acc[q];
}

// ---------------- main persistent kernel ----------------
struct TP {
  const float *mem, *abih, *abhh, *lconv, *llw, *vw, *dbih, *dbhh, *projb, *gateb;
  const int* lens;
  float* ws;
  float* out;
};

// 512 blocks, 2 per CU (LDS 28672B*2, VGPR<=256 via launch_bounds(256,2)).
// bid = (hh<<8) | r ; pair (r, r+256) shares the same XCD (bid%8 equal).
__global__ __launch_bounds__(256, 2) void taco_main(TP p) {
  __shared__ float smem[7168];
  float* const ws = p.ws;
  unsigned epoch = 0;
  const int bid = blockIdx.x, tid = threadIdx.x;
  const int r = bid & 255, hh = bid >> 8;

#pragma unroll 1
  for (int t = 0; t <= 800; ++t) {
    const int par = t & 1, nxt = (t + 1) & 1, prv = (t - 1) & 1;
    // ======== P1: att-fused(t) [r<128] | dec-fused(t-1) [r>=128] ========
    if (r < 128) {
      if (t < 800)
        fused_block(ws + XATT + (size_t)par * 57344 + (size_t)hh * 16 * 1792,
                    1792, ws + WT_ATT + (size_t)r * 1792 * 32, r, hh,
                    p.abih, p.abhh, ws + AC_O,
                    ws + AH_O, 1024,
                    ws + XATT + (size_t)nxt * 57344 + 768, 1792,
                    ws + XDEC + (size_t)par * 81920, 2560, tid, smem);
    } else {
      if (t > 0)
        fused_block(ws + XDEC + (size_t)prv * 81920 + (size_t)hh * 16 * 2560,
                    2560, ws + WT_DEC + (size_t)(r - 128) * 2560 * 32, r - 128,
                    hh, p.dbih, p.dbhh, ws + DC_O,
                    ws + DH_O, 1024,
                    ws + XDEC + (size_t)par * 81920 + 1024, 2560,
                    nullptr, 0, tid, smem);
    }
    gsync(ws, epoch);

    // ======== P2: energies(t) [r<128, both hh] | proj(t-1) [r 128..159,hh=0]
    if (r < 128) {
      if (t < 800) {
        const int b = r >> 2, q8 = ((r & 3) << 1) | hh;  // 64 t_in per block
        float* sa = smem;            // 1024 (ah)
        float* sloc = smem + 1024;   // 64*33 = 2112
        float* pqp = smem + 3136;    // 256
        float* pq = smem + 3392;     // 128
        float* sme = smem + 3520;    // 256
#pragma unroll
        for (int i = 0; i < 4; ++i)
          sa[tid + 256 * i] = gload(ws + AH_O + (size_t)b * 1024 + tid + 256 * i);
#pragma unroll
        for (int ii = 0; ii < 8; ++ii) {
          const int flat = tid + 256 * ii;  // < 2048 (64 ti x 32 f)
          sloc[(flat >> 5) * 33 + (flat & 31)] =
              gload(ws + LOC_O + (size_t)b * 16384 + (size_t)q8 * 2048 + flat);
        }
        __syncthreads();
        {  // pq[j] = ah . qw[j], K split in 2, 4 independent chains
          const int j = tid & 127, kh = tid >> 7;
          const float* qb = ws + QWT + (size_t)kh * 512 * 128 + j;
          const float* ab = sa + kh * 512;
          float a0 = 0, a1 = 0, a2 = 0, a3 = 0;
          for (int k = 0; k < 512; k += 4) {
            a0 = fmaf(qb[(size_t)k * 128], ab[k], a0);
            a1 = fmaf(qb[(size_t)(k + 1) * 128], ab[k + 1], a1);
            a2 = fmaf(qb[(size_t)(k + 2) * 128], ab[k + 2], a2);
            a3 = fmaf(qb[(size_t)(k + 3) * 128], ab[k + 3], a3);
          }
          pqp[tid] = (a0 + a1) + (a2 + a3);
        }
        __syncthreads();
        if (tid < 128) pq[tid] = pqp[tid] + pqp[128 + tid];
        __syncthreads();
        const int ti_l = tid & 63, th = tid >> 6;  // 4-way a-split, 32 a each
        float lr[32];
#pragma unroll
        for (int f = 0; f < 32; ++f) lr[f] = sloc[ti_l * 33 + f];
        const float* pmb = ws + PMEMT + (size_t)b * 65536 +
                           (size_t)(th * 32) * 512 + q8 * 64 + ti_l;
        float acc_e = 0;
#pragma unroll 2
        for (int a0 = 0; a0 < 32; ++a0) {
          const int a = th * 32 + a0;
          float s = pq[a] + pmb[(size_t)a0 * 512];
          const float* la = p.llw + a * 32;
#pragma unroll
          for (int f = 0; f < 32; ++f) s = fmaf(lr[f], la[f], s);
          acc_e = fmaf(p.vw[a], tanh_f(s), acc_e);
        }
        sme[tid] = acc_e;
        __syncthreads();
        if (tid < 64) {
          const int ti = q8 * 64 + tid;
          const float e = sme[tid] + sme[64 + tid] + sme[128 + tid] + sme[192 + tid];
          gstore(ws + ENER_O + (size_t)b * 512 + ti, (ti < p.lens[b]) ? e : -1e9f);
        }
      }
    } else if (r < 160 && hh == 0) {
      if (t > 0) {  // proj(t-1) for b = r-128: 81 outs, K=1536
        const int b = r - 128;
        float* sx = smem;          // 1536
        float* sred = smem + 1536; // 256
#pragma unroll
        for (int i = 0; i < 6; ++i) {
          const int flat = tid + 256 * i;
          sx[flat] = (flat < 1024)
                         ? gload(ws + DH_O + (size_t)b * 1024 + flat)
                         : gload(ws + ACTX_O + (size_t)prv * 16384 + (size_t)b * 512 +
                                 (flat - 1024));
        }
        __syncthreads();
        float p0 = 0.f, p1 = 0.f, p2 = 0.f, p3 = 0.f;
        const int o = tid / 3, ks2 = tid - o * 3;
        if (o < 81) {
          const float* wcol = ws + PWT + o;
          const int k0 = ks2 * 512;
          for (int k = k0; k < k0 + 512; k += 4) {
            p0 = fmaf(sx[k], wcol[(size_t)k * 96], p0);
            p1 = fmaf(sx[k + 1], wcol[(size_t)(k + 1) * 96], p1);
            p2 = fmaf(sx[k + 2], wcol[(size_t)(k + 2) * 96], p2);
            p3 = fmaf(sx[k + 3], wcol[(size_t)(k + 3) * 96], p3);
          }
        }
        sred[tid] = (p0 + p1) + (p2 + p3);
        __syncthreads();
        if (tid < 81) {
          float ssum = sred[tid * 3] + sred[tid * 3 + 1] + sred[tid * 3 + 2];
          ssum += (tid < 80) ? p.projb[tid] : p.gateb[0];
          if (tid < 80)
            p.out[MEL_OUT + ((size_t)b * 80 + tid) * 800 + (t - 1)] = ssum;
          else
            p.out[GATE_OUT + (size_t)b * 800 + (t - 1)] = ssum;
        }
      }
    }
    gsync(ws, epoch);

    // ======== P3: softmax + context + awc + conv(t+1)  [all 512] ========
    if (t < 800) {
      const int b = r >> 3, dc16 = ((r & 7) << 1) | hh;  // 32-d window
      float* se = smem;            // 512
      float* red = smem + 512;     // 256
      float* sp = smem + 768;      // 512
      float* sc = smem + 1280;     // 256
      float* saw = smem + 1536;    // 64 (aw halo)
      float* sawh = smem + 1600;   // 64 (awc_new halo)
      float* slc = smem + 1664;    // 1984 (conv weights)
      se[tid] = gload(ws + ENER_O + (size_t)b * 512 + tid);
      se[256 + tid] = gload(ws + ENER_O + (size_t)b * 512 + 256 + tid);
      for (int i = tid; i < 1984; i += 256) slc[i] = p.lconv[i];
      __syncthreads();
      red[tid] = fmaxf(se[tid], se[256 + tid]);
      __syncthreads();
      for (int s = 128; s > 0; s >>= 1) {
        if (tid < s) red[tid] = fmaxf(red[tid], red[tid + s]);
        __syncthreads();
      }
      const float mx = red[0];
      __syncthreads();
      const float p0 = __expf(se[tid] - mx), p1 = __expf(se[256 + tid] - mx);
      sp[tid] = p0;
      sp[256 + tid] = p1;
      red[tid] = p0 + p1;
      __syncthreads();
      for (int s = 128; s > 0; s >>= 1) {
        if (tid < s) red[tid] += red[tid + s];
        __syncthreads();
      }
      const float inv = 1.f / red[0];
      // context: this block covers d in [dc16*32, +32); 8 i-segments
      const int tseg = tid >> 5, dl = tid & 31;
      const int base = dc16 * 32;
      const float* mrow =
          p.mem + ((size_t)b * 512 + tseg * 64) * 512 + base + dl;
      float ca = 0, cb = 0;
      for (int i = 0; i < 64; i += 2) {
        ca = fmaf(sp[tseg * 64 + i], mrow[(size_t)i * 512], ca);
        cb = fmaf(sp[tseg * 64 + i + 1], mrow[(size_t)(i + 1) * 512], cb);
      }
      sc[tid] = ca + cb;
      // aw / awc_new halo for conv: 62 entries [base-15, base+46]
      for (int i = tid; i < 62; i += 256) {
        const int x = base - 15 + i;
        const bool ok = (unsigned)x < 512u;
        const float awx = ok ? sp[x] * inv : 0.f;
        saw[i] = awx;
        sawh[i] = awx + (ok ? gload(ws + AWC_O + (size_t)par * 16384 +
                                    (size_t)b * 512 + x)
                            : 0.f);
      }
      __syncthreads();
      if (tid < 32) {
        float v = sc[tid] + sc[32 + tid] + sc[64 + tid] + sc[96 + tid] +
                  sc[128 + tid] + sc[160 + tid] + sc[192 + tid] + sc[224 + tid];
        v *= inv;
        const int dd = base + tid;
        gstore(ws + ACTX_O + (size_t)par * 16384 + (size_t)b * 512 + dd, v);
        gstore(ws + XATT + (size_t)nxt * 57344 + (size_t)b * 1792 + 256 + dd, v);
        gstore(ws + XDEC + (size_t)par * 81920 + (size_t)b * 2560 + 2048 + dd, v);
        gstore(ws + AWC_O + (size_t)nxt * 16384 + (size_t)b * 512 + dd,
               sawh[15 + tid]);
        p.out[ALIGN_OUT + ((size_t)b * 800 + t) * 512 + dd] = sp[dd] * inv;
      }
      if (t + 1 < 800) {
        // conv for step t+1 over this block's 32-wide t_in slice
        const int f = tid & 31, tig = tid >> 5;
#pragma unroll 2
        for (int tt = 0; tt < 4; ++tt) {
          const int til = tig + tt * 8;
          float a2 = 0;
#pragma unroll
          for (int k2 = 0; k2 < 31; ++k2) a2 = fmaf(saw[til + k2], slc[f * 62 + k2], a2);
#pragma unroll
          for (int k2 = 0; k2 < 31; ++k2)
            a2 = fmaf(sawh[til + k2], slc[f * 62 + 31 + k2], a2);
          gstore(ws + LOC_O + (size_t)b * 16384 + (size_t)(base + til) * 32 + f, a2);
        }
        // pren(t+1) -> XATT[nxt]
        if (dc16 < 8 && tid < 32) {
          const int cc = dc16 * 32 + tid;
          gstore(ws + XATT + (size_t)nxt * 57344 + (size_t)b * 1792 + cc,
                 ws[PREN_O + ((size_t)(t + 1) * 32 + b) * 256 + cc]);
        }
      }
    }
    gsync(ws, epoch);
  }
}

// ---------------- launch ----------------
extern "C" void kernel_launch(void* const* d_in, const int* in_sizes, int n_in,
                              void* d_out, int out_size, void* d_ws, size_t ws_size,
                              hipStream_t stream) {
  (void)in_sizes; (void)n_in; (void)out_size; (void)ws_size;
  const float* mem = (const float*)d_in[0];
  const float* decin = (const float*)d_in[1];
  const float* w1 = (const float*)d_in[2];
  const float* w2 = (const float*)d_in[3];
  const float* awih = (const float*)d_in[4];
  const float* awhh = (const float*)d_in[5];
  const float* abih = (const float*)d_in[6];
  const float* abhh = (const float*)d_in[7];
  const float* qw = (const float*)d_in[8];
  const float* memw = (const float*)d_in[9];
  const float* vw = (const float*)d_in[10];
  const float* lconv = (const float*)d_in[11];
  const float* llw = (const float*)d_in[12];
  const float* dwih = (const float*)d_in[13];
  const float* dwhh = (const float*)d_in[14];
  const float* dbih = (const float*)d_in[15];
  const float* dbhh = (const float*)d_in[16];
  const float* projw = (const float*)d_in[17];
  const float* projb = (const float*)d_in[18];
  const float* gatew = (const float*)d_in[19];
  const float* gateb = (const float*)d_in[20];
  const int* lens = (const int*)d_in[21];
  float* ws = (float*)d_ws;
  float* out = (float*)d_out;

  // zero: X buffers (pren(0)=0, ah(-1)=0, dh(-1)=0, actx(-1)=0),
  // state AH..DC, AWC, ACTX, ENER, LOC, and barrier lines.
  hipMemsetAsync(ws + XATT, 0, (114688 + 163840) * sizeof(float), stream);
  hipMemsetAsync(ws + AH_O, 0, 737280 * sizeof(float), stream);
  hipMemsetAsync(ws + BAR_O, 0, 4224 * sizeof(unsigned), stream);

  k_small<<<1680, 256, 0, stream>>>(w1, w2, qw, memw, projw, gatew, ws);
  k_tr_a_wih<<<12288, 256, 0, stream>>>(awih, ws);
  k_tr_a_whh<<<16384, 256, 0, stream>>>(awhh, ws);
  k_tr_d_wih<<<24576, 256, 0, stream>>>(dwih, ws);
  k_tr_d_whh<<<16384, 256, 0, stream>>>(dwhh, ws);
  k_prenet<<<dim3(100, 32), 256, 0, stream>>>(decin, ws);
  k_pmem<<<dim3(32, 32), 256, 0, stream>>>(mem, ws);

  TP tp{mem, abih, abhh, lconv, llw, vw, dbih, dbhh, projb, gateb, lens, ws, out};
  taco_main<<<512, 256, 0, stream>>>(tp);
}